// Round 14
// baseline (753.519 us; speedup 1.0000x reference)
//
#include <hip/hip_runtime.h>
#include <math.h>

#define B 64
#define CIN 2
#define CH 32
#define H 128
#define W 128
#define MODES 12
#define KY 24              // kept ky rows: 0..11 and 116..127
#define KX 12              // kept kx cols
#define HW (H*W)           // 16384
#define NMODE (KY*KX)      // 288

typedef float f32x2 __attribute__((ext_vector_type(2)));
typedef unsigned short u16;
typedef unsigned int u32;
__device__ __forceinline__ f32x2 mk2(float a, float b) { f32x2 r; r.x = a; r.y = b; return r; }

// bf16 <-> f32 (h stored as bf16: halves the 1.6GB of h HBM traffic)
__device__ __forceinline__ float bflo(u32 u) { return __uint_as_float(u << 16); }
__device__ __forceinline__ float bfhi(u32 u) { return __uint_as_float(u & 0xFFFF0000u); }
__device__ __forceinline__ u16 f2bf(float f) {            // RTNE
    u32 u = __float_as_uint(f);
    return (u16)((u + 0x7FFFu + ((u >> 16) & 1u)) >> 16);
}

// tanh-form GELU, 8 VALU ops. 0.5x(1+tanh(y)) == x*(1 - 1/(e^{2y}+1));
// |err| vs exact erf-GELU ~3e-4, damped by mixing+pooling+sigmoid.
__device__ __forceinline__ float gelu_f(float x) {
    float x2 = x * x;
    float d  = x * (1.5957691216057308f + 0.0713548162726009f * x2);  // 2y
    float e  = __expf(d);
    float r  = __builtin_amdgcn_rcpf(e + 1.0f);
    return x - x * r;                       // x*(1-r); d->+inf: r=0 -> x
}

// ---------------- twiddle tables ----------------
// cWkw/sWkw  [k][w] scalar   : k_fused irfft per-lane loads (r3-proven)
// cnsWkw     [k][w]{c,-s}    : k-major pairs; k_dft_w v3 wave-uniform s_loads
// cnsH2/mnsH2[h][ky]{c,s}/{-s,c}: k_dft_h (per-lane) / k_idft_h (uniform)
__global__ __launch_bounds__(256) void k_init_tables(
        float* cWkw, float* sWkw, float* cnsWkw,
        float* cnsH2, float* mnsH2) {
    int t = blockIdx.x * 256 + threadIdx.x;
    const float TWO_PI_OVER = 6.283185307179586476925f / 128.0f;
    if (t < MODES * W) {
        int k = t / W, w = t % W;
        int m = (k * w) & 127;
        float s, c;
        sincosf(TWO_PI_OVER * (float)m, &s, &c);
        cWkw[k * W + w] = c;  sWkw[k * W + w] = s;
        cnsWkw[(k * W + w) * 2]     = c;
        cnsWkw[(k * W + w) * 2 + 1] = -s;
    } else if (t < MODES * W + KY * H) {
        int u = t - MODES * W;
        int kyI = u / H, hh = u % H;
        int ky = (kyI < MODES) ? kyI : (H - MODES + (kyI - MODES));  // 116..127
        int m = (ky * hh) & 127;
        float s, c;
        sincosf(TWO_PI_OVER * (float)m, &s, &c);
        cnsH2[(hh * KY + kyI) * 2]     = c;
        cnsH2[(hh * KY + kyI) * 2 + 1] = s;
        mnsH2[(hh * KY + kyI) * 2]     = -s;
        mnsH2[(hh * KY + kyI) * 2 + 1] = c;
    }
}

// ---------------- weight reorder: wR[layer][m][i][o]{re,im}, m = kyI*KX+kx ---
__global__ __launch_bounds__(256) void k_reorder_w(
        const float* __restrict__ w1r, const float* __restrict__ w1i,
        const float* __restrict__ w2r, const float* __restrict__ w2i,
        float* __restrict__ wR) {
    int idx = blockIdx.x * 256 + threadIdx.x;   // 4*288*1024
    if (idx >= 4 * NMODE * CH * CH) return;
    int o = idx & 31;
    int i = (idx >> 5) & 31;
    int m = (idx >> 10) % NMODE;
    int layer = idx / (NMODE * CH * CH);
    int kyI = m / KX, kx = m % KX;
    const float *sr, *si;
    int row;
    if (kyI < MODES) { sr = w1r; si = w1i; row = kyI; }
    else             { sr = w2r; si = w2i; row = kyI - MODES; }
    int src = ((layer * CH + i) * CH + o) * (MODES * MODES) + row * MODES + kx;
    wR[(size_t)idx * 2]     = sr[src];
    wR[(size_t)idx * 2 + 1] = si[src];
}

// ---------------- ww transpose: wwT[layer][i][o] = ww[layer][o][i] ----------
__global__ __launch_bounds__(256) void k_transpose_ww(
        const float* __restrict__ ww, float* __restrict__ wwT) {
    int idx = blockIdx.x * 256 + threadIdx.x;
    if (idx >= 4 * CH * CH) return;
    int l = idx / (CH * CH);
    int r = idx % (CH * CH);
    int i = r / CH, o = r % CH;
    wwT[idx] = ww[l * CH * CH + o * CH + i];
}

// ---------------- lifting conv3x3 circular: x[B,2,H,W] -> h(bf16) -----------
__global__ __launch_bounds__(128) void k_lift(
        const float* __restrict__ x, const float* __restrict__ pw,
        const float* __restrict__ pb, u16* __restrict__ h) {
    int bh = blockIdx.x;            // b*H + hr
    int b = bh >> 7, hr = bh & 127;
    int w = threadIdx.x;
    int wl = (w + W - 1) & (W - 1), wr2 = (w + 1) & (W - 1);
    float xv[CIN][3][3];
    #pragma unroll
    for (int ic = 0; ic < CIN; ++ic) {
        const float* xc = x + (size_t)(b * CIN + ic) * HW;
        #pragma unroll
        for (int r = 0; r < 3; ++r) {
            int hh = (hr + r - 1 + H) & (H - 1);
            const float* xr = xc + hh * W;
            xv[ic][r][0] = xr[wl];
            xv[ic][r][1] = xr[w];
            xv[ic][r][2] = xr[wr2];
        }
    }
    for (int o = 0; o < CH; ++o) {
        float acc = pb[o];                       // uniform -> s_load
        const float* wo = pw + o * CIN * 9;      // uniform
        #pragma unroll
        for (int ic = 0; ic < CIN; ++ic)
            #pragma unroll
            for (int r = 0; r < 3; ++r)
                #pragma unroll
                for (int c3 = 0; c3 < 3; ++c3)
                    acc += xv[ic][r][c3] * wo[ic * 9 + r * 3 + c3];
        h[(size_t)(b * CH + o) * HW + hr * W + w] = f2bf(acc);
    }
}

// ---------------- DFT along W: h(bf16) rows -> Xw[row][k]{re,im} ------------
// v3 structure; bf16 staging now float4-granular: thread -> (row=idx>>5,
// f4col=idx&31), uint2 load (4 bf16, 8B/lane coalesced), ONE float4 LDS
// write (consecutive lanes -> consecutive 16B -> conflict-free). r13's
// 8-floats-per-lane layout hit 4-16-way bank conflicts (1M/dispatch).
__global__ __launch_bounds__(256) void k_dft_w(
        const u16* __restrict__ h, const float* __restrict__ cnsWkw,
        float* __restrict__ Xw) {
    __shared__ float xs[64 * 129];       // 33 KB
    int row0 = blockIdx.x * 64;
    int tid = threadIdx.x;
    const uint2* src = (const uint2*)h;  // 4 bf16 per uint2
    #pragma unroll
    for (int it = 0; it < 8; ++it) {     // 2048 float4-slots, conflict-free
        int idx = it * 256 + tid;
        int r = idx >> 5, f4c = idx & 31;
        uint2 v = src[(size_t)(row0 + r) * 32 + f4c];
        float4 f;
        f.x = bflo(v.x); f.y = bfhi(v.x);
        f.z = bflo(v.y); f.w = bfhi(v.y);
        *(float4*)(xs + r * 129 + f4c * 4) = f;
    }
    __syncthreads();
    int r = tid & 63;
    int kp = __builtin_amdgcn_readfirstlane(tid >> 6);   // 0..3, wave-uniform
    const f32x2* tw = (const f32x2*)cnsWkw + kp * 3 * W; // k = 3kp..3kp+2
    f32x2 a0 = mk2(0.f, 0.f), a1 = mk2(0.f, 0.f), a2 = mk2(0.f, 0.f);
    const float* xr = xs + r * 129;
    #pragma unroll 4
    for (int w = 0; w < W; ++w) {
        float xv = xr[w];                // ds_read_b32, 2-way max (free)
        f32x2 x2 = mk2(xv, xv);
        a0 += x2 * tw[w];                // uniform -> s_load + v_pk_fma
        a1 += x2 * tw[W + w];
        a2 += x2 * tw[2 * W + w];
    }
    float2* dst = (float2*)(Xw + (size_t)(row0 + r) * MODES * 2) + kp * 3;
    dst[0] = make_float2(a0.x, a0.y);
    dst[1] = make_float2(a1.x, a1.y);
    dst[2] = make_float2(a2.x, a2.y);
}

// ---------------- DFT along H: Xw -> Xf[m][b*CH+c]{re,im} -------------------
// One block per bc (2048 blocks); stage the 12KB Xw row in LDS coalesced;
// 288 threads own one (ky,kx) each.
__global__ __launch_bounds__(320) void k_dft_h(
        const float* __restrict__ Xw, const float* __restrict__ cnsH2,
        float* __restrict__ Xf) {
    __shared__ float4 xs4[H * KX / 2];   // 12 KB, aliased as float2[H][KX]
    const float2* xs = (const float2*)xs4;
    int bc = blockIdx.x;                 // 0..B*CH-1
    int tid = threadIdx.x;               // 0..319
    const float4* src = (const float4*)(Xw + (size_t)bc * H * KX * 2);
    #pragma unroll
    for (int r = 0; r < 3; ++r) {        // 768 float4 staged by 320 threads
        int idx = r * 320 + tid;
        if (idx < H * KX / 2) xs4[idx] = src[idx];
    }
    __syncthreads();
    if (tid < KY * KX) {                 // m = tid = ky*KX+kx
        int ky = tid / KX, kx = tid % KX;
        const float2* cs = (const float2*)cnsH2 + ky;   // [hh][ky] stride KY
        float ar = 0.f, ai = 0.f;
        #pragma unroll 4
        for (int hh = 0; hh < H; ++hh) {
            float2 v = xs[hh * KX + kx];                 // LDS broadcast groups
            float2 t = cs[hh * KY];                      // L1-resident table
            ar += v.x * t.x + v.y * t.y;                 // (xr+ixi)(c-is)
            ai += v.y * t.x - v.x * t.y;
        }
        ((float2*)Xf)[(size_t)tid * (B * CH) + bc] = make_float2(ar, ai);
    }
}

// ---------------- spectral channel mix: per mode, Y[b,o] = sum_i X[b,i]W[i,o]
// Output layout Yt[b][m][o]{re,im} (o minor -> coalesced, feeds k_idft_h).
__global__ __launch_bounds__(256) void k_specmul(
        const float* __restrict__ Xf, const float* __restrict__ wRl,
        float* __restrict__ Yt) {
    int m = blockIdx.x;                 // 0..287
    int o = threadIdx.x & 31;
    int bq = threadIdx.x >> 5;          // 0..7 -> 8 b's each
    const f32x2* X  = (const f32x2*)Xf  + (size_t)m * (B * CH);
    const f32x2* Wm = (const f32x2*)wRl + (size_t)m * (CH * CH);
    f32x2 acc2[8];
    #pragma unroll
    for (int j = 0; j < 8; ++j) acc2[j] = mk2(0.f, 0.f);
    for (int i = 0; i < CH; ++i) {
        f32x2 wv  = Wm[i * CH + o];     // coalesced across lanes
        f32x2 wvB = mk2(-wv.y, wv.x);
        #pragma unroll
        for (int j = 0; j < 8; ++j) {
            f32x2 xv = X[(bq * 8 + j) * CH + i];   // L1/L2 broadcast
            acc2[j] += mk2(xv.x, xv.x) * wv + mk2(xv.y, xv.y) * wvB;  // 2 pk_fma
        }
    }
    float2* Yp = (float2*)Yt;
    #pragma unroll
    for (int j = 0; j < 8; ++j)
        Yp[((size_t)(bq * 8 + j) * NMODE + m) * CH + o] = make_float2(acc2[j].x, acc2[j].y);
}

// ---------------- inverse DFT along H: Yt -> Zt[b][h][p][kx][o], pre-scaled -
// acc = (re,im) pairs; twiddle pairs (c,s)/(-s,c) uniform -> s_load.
__global__ __launch_bounds__(384) void k_idft_h(
        const float* __restrict__ Yt, const float* __restrict__ cnsH2,
        const float* __restrict__ mnsH2, float* __restrict__ Zt) {
    int b = blockIdx.x;
    int hh0 = blockIdx.y * 16;           // 8 chunks of 16 rows
    int o = threadIdx.x & 31;
    int kx = threadIdx.x >> 5;           // 0..11
    float yr[KY], yi[KY];
    #pragma unroll
    for (int ky = 0; ky < KY; ++ky) {
        float2 v = ((const float2*)Yt)[((size_t)b * NMODE + ky * KX + kx) * CH + o];
        yr[ky] = v.x;  yi[ky] = v.y;
    }
    float sc = (kx == 0 ? 1.0f : 2.0f) / (float)HW;
    #pragma unroll 2
    for (int hr = 0; hr < 16; ++hr) {
        int hh = hh0 + hr;
        const f32x2* cs = (const f32x2*)(cnsH2 + hh * KY * 2);  // uniform
        const f32x2* ms = (const f32x2*)(mnsH2 + hh * KY * 2);  // uniform
        f32x2 a = mk2(0.f, 0.f);
        #pragma unroll
        for (int ky = 0; ky < KY; ++ky)
            a += mk2(yr[ky], yr[ky]) * cs[ky] + mk2(yi[ky], yi[ky]) * ms[ky];
        size_t base = ((size_t)(b * H + hh) * 2) * (KX * CH) + kx * CH + o;
        Zt[base]            = a.x * sc;
        Zt[base + KX * CH]  = a.y * sc;
    }
}

// ---------------- fused: pointwise GEMM + irfft(W) + bias + GELU ------------
// r13 pk body; bf16 staging now float4-granular conflict-free (two passes of
// uint2-load + float4-LDS-write). LAST=0: write gelu(h) in place. LAST=1:
// per-block partials -> part (no global atomics).
template <int LAST>
__global__ __launch_bounds__(512, 4) void k_fused(
        u16* __restrict__ h, const float* __restrict__ Zt,
        const float* __restrict__ wwT, const float* __restrict__ wb,
        const float* __restrict__ cWkw, const float* __restrict__ sWkw,
        float* __restrict__ part) {
    __shared__ float hs[CH * W];         // 16 KB
    __shared__ float red[8][8];          // wave partials (LAST=1 only)
    int bh = blockIdx.x;                 // b*H + hr
    int b = bh >> 7, hr = bh & 127;
    int tid = threadIdx.x;
    int w = tid & 127;
    int og = __builtin_amdgcn_readfirstlane(tid >> 7);   // wave-uniform 0..3
    const uint2* hrow2 = (const uint2*)(h + (size_t)b * CH * HW + hr * W);
    #pragma unroll
    for (int p = 0; p < 2; ++p) {        // 1024 float4-slots, conflict-free
        int idx = p * 512 + tid;
        int i = idx >> 5, f4c = idx & 31;
        uint2 v = hrow2[(size_t)i * (HW / 4) + f4c];
        float4 f;
        f.x = bflo(v.x); f.y = bfhi(v.x);
        f.z = bflo(v.y); f.w = bfhi(v.y);
        *(float4*)(hs + i * W + f4c * 4) = f;
    }
    float ck[MODES], nsk[MODES];
    #pragma unroll
    for (int k = 0; k < MODES; ++k) {
        ck[k]  = cWkw[k * W + w];        // per-lane, coalesced, L1-hot
        nsk[k] = -sWkw[k * W + w];
    }
    f32x2 acc2[4];
    const f32x2* wb2 = (const f32x2*)(wb + og * 8);      // uniform
    #pragma unroll
    for (int j = 0; j < 4; ++j) acc2[j] = wb2[j];
    __syncthreads();
    // pointwise: acc2[j] += hs[i][w] * wwT[i][og*8+2j..2j+1]
    #pragma unroll 4
    for (int i = 0; i < CH; ++i) {
        float hv = hs[i * W + w];
        f32x2 hv2 = mk2(hv, hv);
        const f32x2* wt2 = (const f32x2*)(wwT + i * CH + og * 8);  // uniform
        #pragma unroll
        for (int j = 0; j < 4; ++j) acc2[j] += hv2 * wt2[j];       // pk_fma
    }
    // spectral: acc2[j] += zr*ck - zi*sk  (pre-scaled in Zt)
    const float* Zb = Zt + ((size_t)bh * 2) * (KX * CH) + og * 8;
    #pragma unroll
    for (int k = 0; k < MODES; ++k) {
        const f32x2* zr2 = (const f32x2*)(Zb + k * CH);            // uniform
        const f32x2* zi2 = (const f32x2*)(Zb + k * CH + KX * CH);
        f32x2 ck2  = mk2(ck[k], ck[k]);
        f32x2 nsk2 = mk2(nsk[k], nsk[k]);
        #pragma unroll
        for (int j = 0; j < 4; ++j)
            acc2[j] += zr2[j] * ck2 + zi2[j] * nsk2;               // 2 pk_fma
    }
    if (LAST == 0) {
        u16* hout = h + (size_t)(b * CH + og * 8) * HW + hr * W + w;
        #pragma unroll
        for (int j = 0; j < 4; ++j) {
            hout[(size_t)(2 * j)     * HW] = f2bf(gelu_f(acc2[j].x));
            hout[(size_t)(2 * j + 1) * HW] = f2bf(gelu_f(acc2[j].y));
        }
    } else {
        float v[8];
        #pragma unroll
        for (int j = 0; j < 4; ++j) {
            v[2 * j]     = gelu_f(acc2[j].x);
            v[2 * j + 1] = gelu_f(acc2[j].y);
        }
        #pragma unroll
        for (int j = 0; j < 8; ++j)
            #pragma unroll
            for (int off = 32; off > 0; off >>= 1)
                v[j] += __shfl_xor(v[j], off, 64);
        int wave = tid >> 6;             // 0..7 (wave>>1 == og)
        if ((tid & 63) == 0) {
            #pragma unroll
            for (int j = 0; j < 8; ++j) red[wave][j] = v[j];
        }
        __syncthreads();
        if (tid < CH) {                  // c = tid: og=c>>3, j=c&7
            float p = red[2 * (tid >> 3)][tid & 7] + red[2 * (tid >> 3) + 1][tid & 7];
            part[((size_t)b * CH + tid) * H + hr] = p;
        }
    }
}

// ---------------- reduce partials -> g[b][c] (mean folded) ------------------
__global__ __launch_bounds__(64) void k_reduce(
        const float* __restrict__ part, float* __restrict__ g) {
    int bc = blockIdx.x;                 // 0..B*CH-1
    int t = threadIdx.x;                 // 0..63
    float s = part[(size_t)bc * H + t] + part[(size_t)bc * H + 64 + t];
    #pragma unroll
    for (int off = 32; off > 0; off >>= 1) s += __shfl_down(s, off, 64);
    if (t == 0) g[bc] = s * (1.0f / (float)HW);
}

// ---------------- head MLP: 32 -> 128 gelu -> 1 -> sigmoid ------------------
__global__ __launch_bounds__(128) void k_head(
        const float* __restrict__ g, const float* __restrict__ q1w,
        const float* __restrict__ q1b, const float* __restrict__ q2w,
        const float* __restrict__ q2b, float* __restrict__ out) {
    __shared__ float gs[CH];
    __shared__ float red2[2];
    int b = blockIdx.x;
    int t = threadIdx.x;
    if (t < CH) gs[t] = g[b * CH + t];
    __syncthreads();
    float a = q1b[t];
    #pragma unroll
    for (int c = 0; c < CH; ++c) a += gs[c] * q1w[t * CH + c];
    a = gelu_f(a);
    float hsum = a * q2w[t];
    #pragma unroll
    for (int off = 32; off > 0; off >>= 1) hsum += __shfl_down(hsum, off, 64);
    if ((t & 63) == 0) red2[t >> 6] = hsum;
    __syncthreads();
    if (t == 0) {
        float logit = red2[0] + red2[1] + q2b[0];
        out[b] = 1.0f / (1.0f + expf(-logit));
    }
}

extern "C" void kernel_launch(void* const* d_in, const int* in_sizes, int n_in,
                              void* d_out, int out_size, void* d_ws, size_t ws_size,
                              hipStream_t stream) {
    const float* x   = (const float*)d_in[0];
    const float* p_w = (const float*)d_in[1];
    const float* p_b = (const float*)d_in[2];
    const float* w1r = (const float*)d_in[3];
    const float* w1i = (const float*)d_in[4];
    const float* w2r = (const float*)d_in[5];
    const float* w2i = (const float*)d_in[6];
    const float* ww  = (const float*)d_in[7];
    const float* wb  = (const float*)d_in[8];
    const float* q1w = (const float*)d_in[9];
    const float* q1b = (const float*)d_in[10];
    const float* q2w = (const float*)d_in[11];
    const float* q2b = (const float*)d_in[12];
    float* out = (float*)d_out;

    float* ws = (float*)d_ws;
    size_t off = 0;
    auto alloc = [&](size_t n) {
        float* p = ws + off;
        off += (n + 63) & ~(size_t)63;   // 256B-align
        return p;
    };
    float* cWkw   = alloc(MODES * W);
    float* sWkw   = alloc(MODES * W);
    float* cnsWkw = alloc(MODES * W * 2);
    float* cnsH2  = alloc(H * KY * 2);
    float* mnsH2  = alloc(H * KY * 2);
    u16*   hBuf = (u16*)alloc((size_t)B * CH * HW / 2);  // 67 MB bf16
    float* XwZ  = alloc((size_t)B * CH * H * KX * 2);    // 25 MB (Xw, reused as Zt)
    float* Xf   = alloc((size_t)NMODE * B * CH * 2);     // 4.7 MB
    float* Yt   = alloc((size_t)B * NMODE * CH * 2);     // 4.7 MB
    float* wR   = alloc((size_t)4 * NMODE * CH * CH * 2);// 9.4 MB
    float* wwT  = alloc(4 * CH * CH);
    float* part = alloc((size_t)B * CH * H);             // 1 MB block partials
    float* g    = alloc(B * CH);

    // tables + weight layouts (recomputed every call: deterministic)
    k_init_tables<<<(MODES * W + KY * H + 255) / 256, 256, 0, stream>>>(
        cWkw, sWkw, cnsWkw, cnsH2, mnsH2);
    k_reorder_w<<<(4 * NMODE * CH * CH + 255) / 256, 256, 0, stream>>>(
        w1r, w1i, w2r, w2i, wR);
    k_transpose_ww<<<(4 * CH * CH + 255) / 256, 256, 0, stream>>>(ww, wwT);

    k_lift<<<B * H, 128, 0, stream>>>(x, p_w, p_b, hBuf);

    for (int layer = 0; layer < 4; ++layer) {
        k_dft_w<<<(B * CH * H) / 64, 256, 0, stream>>>(hBuf, cnsWkw, XwZ);
        k_dft_h<<<B * CH, 320, 0, stream>>>(XwZ, cnsH2, Xf);
        k_specmul<<<NMODE, 256, 0, stream>>>(
            Xf, wR + (size_t)layer * NMODE * CH * CH * 2, Yt);
        k_idft_h<<<dim3(B, 8), 384, 0, stream>>>(Yt, cnsH2, mnsH2, XwZ);
        if (layer < 3)
            k_fused<0><<<B * H, 512, 0, stream>>>(
                hBuf, XwZ, wwT + layer * CH * CH, wb + layer * CH, cWkw, sWkw, part);
        else
            k_fused<1><<<B * H, 512, 0, stream>>>(
                hBuf, XwZ, wwT + layer * CH * CH, wb + layer * CH, cWkw, sWkw, part);
    }

    k_reduce<<<B * CH, 64, 0, stream>>>(part, g);
    k_head<<<B, 128, 0, stream>>>(g, q1w, q1b, q2w, q2b, out);
}

// Round 15
// 742.659 us; speedup vs baseline: 1.0146x; 1.0146x over previous
//
#include <hip/hip_runtime.h>
#include <hip/hip_bf16.h>
#include <math.h>

#define B 64
#define CIN 2
#define CH 32
#define H 128
#define W 128
#define MODES 12
#define KY 24              // kept ky rows: 0..11 and 116..127
#define KX 12              // kept kx cols
#define HW (H*W)           // 16384
#define NMODE (KY*KX)      // 288

typedef float f32x2 __attribute__((ext_vector_type(2)));
typedef unsigned short u16;
typedef unsigned int u32;
__device__ __forceinline__ f32x2 mk2(float a, float b) { f32x2 r; r.x = a; r.y = b; return r; }

// bf16 <-> f32 (h stored as bf16: halves h HBM traffic)
__device__ __forceinline__ float bflo(u32 u) { return __uint_as_float(u << 16); }
__device__ __forceinline__ float bfhi(u32 u) { return __uint_as_float(u & 0xFFFF0000u); }
__device__ __forceinline__ u16 f2bf(float f) {            // RTNE (lift only)
    u32 u = __float_as_uint(f);
    return (u16)((u + 0x7FFFu + ((u >> 16) & 1u)) >> 16);
}
// packed f32x2 -> 2 bf16 in one u32 (compiler: v_cvt_pk_bf16_f32)
__device__ __forceinline__ u32 pk2bf(f32x2 v) {
    __hip_bfloat162 p = __float22bfloat162_rn(make_float2(v.x, v.y));
    return *reinterpret_cast<u32*>(&p);
}

// tanh-form GELU. scalar (head/lift) ...
__device__ __forceinline__ float gelu_f(float x) {
    float x2 = x * x;
    float d  = x * (1.5957691216057308f + 0.0713548162726009f * x2);  // 2y
    float e  = __expf(d);
    float r  = __builtin_amdgcn_rcpf(e + 1.0f);
    return x - x * r;
}
// ... and packed-pair version for fused (pk_mul/pk_fma on the polynomial,
// packed e+1 and final x-x*r; only exp/rcp stay scalar): ~12 ops vs 16.
__device__ __forceinline__ f32x2 gelu2(f32x2 x) {
    const f32x2 c1 = mk2(1.5957691216057308f, 1.5957691216057308f);
    const f32x2 c2 = mk2(0.0713548162726009f, 0.0713548162726009f);
    f32x2 x2 = x * x;                        // pk_mul
    f32x2 d  = x * (c1 + c2 * x2);           // pk_fma + pk_mul
    f32x2 e  = mk2(__expf(d.x), __expf(d.y));
    f32x2 ep = e + mk2(1.0f, 1.0f);          // pk_add
    f32x2 r  = mk2(__builtin_amdgcn_rcpf(ep.x), __builtin_amdgcn_rcpf(ep.y));
    return x - x * r;                        // pk_fma-ish
}

// ---------------- one setup kernel (tables + weight reorder + ww transpose) -
// cWkw/sWkw  [k][w] scalar   : k_fused irfft per-lane loads
// cnsWkw     [k][w]{c,-s}    : k_dft_w wave-uniform s_loads
// cnsH2/mnsH2[h][ky]{c,s}/{-s,c}: k_dft_h (per-lane) / k_idft_h (uniform)
// wR[layer][m][i][o]{re,im}  : specmul weights, m = kyI*KX+kx
// wwT[layer][i][o]           : pointwise weights transposed
#define N_TBL (MODES * W + KY * H)           // 4608
#define N_TRN (4 * CH * CH)                  // 4096
#define N_REO (4 * NMODE * CH * CH)          // 1179648
__global__ __launch_bounds__(256) void k_setup(
        float* cWkw, float* sWkw, float* cnsWkw, float* cnsH2, float* mnsH2,
        const float* __restrict__ w1r, const float* __restrict__ w1i,
        const float* __restrict__ w2r, const float* __restrict__ w2i,
        float* __restrict__ wR,
        const float* __restrict__ ww, float* __restrict__ wwT) {
    int t = blockIdx.x * 256 + threadIdx.x;
    const float TWO_PI_OVER = 6.283185307179586476925f / 128.0f;
    if (t < MODES * W) {
        int k = t / W, w = t % W;
        int m = (k * w) & 127;
        float s, c;
        sincosf(TWO_PI_OVER * (float)m, &s, &c);
        cWkw[k * W + w] = c;  sWkw[k * W + w] = s;
        cnsWkw[(k * W + w) * 2]     = c;
        cnsWkw[(k * W + w) * 2 + 1] = -s;
    } else if (t < N_TBL) {
        int u = t - MODES * W;
        int kyI = u / H, hh = u % H;
        int ky = (kyI < MODES) ? kyI : (H - MODES + (kyI - MODES));  // 116..127
        int m = (ky * hh) & 127;
        float s, c;
        sincosf(TWO_PI_OVER * (float)m, &s, &c);
        cnsH2[(hh * KY + kyI) * 2]     = c;
        cnsH2[(hh * KY + kyI) * 2 + 1] = s;
        mnsH2[(hh * KY + kyI) * 2]     = -s;
        mnsH2[(hh * KY + kyI) * 2 + 1] = c;
    } else if (t < N_TBL + N_TRN) {
        int idx = t - N_TBL;
        int l = idx / (CH * CH);
        int r = idx % (CH * CH);
        int i = r / CH, o = r % CH;
        wwT[idx] = ww[l * CH * CH + o * CH + i];
    } else {
        int idx = t - N_TBL - N_TRN;
        if (idx >= N_REO) return;
        int o = idx & 31;
        int i = (idx >> 5) & 31;
        int m = (idx >> 10) % NMODE;
        int layer = idx / (NMODE * CH * CH);
        int kyI = m / KX, kx = m % KX;
        const float *sr, *si;
        int row;
        if (kyI < MODES) { sr = w1r; si = w1i; row = kyI; }
        else             { sr = w2r; si = w2i; row = kyI - MODES; }
        int src = ((layer * CH + i) * CH + o) * (MODES * MODES) + row * MODES + kx;
        wR[(size_t)idx * 2]     = sr[src];
        wR[(size_t)idx * 2 + 1] = si[src];
    }
}

// ---------------- lifting conv3x3 circular: x[B,2,H,W] -> h(bf16) -----------
__global__ __launch_bounds__(128) void k_lift(
        const float* __restrict__ x, const float* __restrict__ pw,
        const float* __restrict__ pb, u16* __restrict__ h) {
    int bh = blockIdx.x;            // b*H + hr
    int b = bh >> 7, hr = bh & 127;
    int w = threadIdx.x;
    int wl = (w + W - 1) & (W - 1), wr2 = (w + 1) & (W - 1);
    float xv[CIN][3][3];
    #pragma unroll
    for (int ic = 0; ic < CIN; ++ic) {
        const float* xc = x + (size_t)(b * CIN + ic) * HW;
        #pragma unroll
        for (int r = 0; r < 3; ++r) {
            int hh = (hr + r - 1 + H) & (H - 1);
            const float* xr = xc + hh * W;
            xv[ic][r][0] = xr[wl];
            xv[ic][r][1] = xr[w];
            xv[ic][r][2] = xr[wr2];
        }
    }
    for (int o = 0; o < CH; ++o) {
        float acc = pb[o];                       // uniform -> s_load
        const float* wo = pw + o * CIN * 9;      // uniform
        #pragma unroll
        for (int ic = 0; ic < CIN; ++ic)
            #pragma unroll
            for (int r = 0; r < 3; ++r)
                #pragma unroll
                for (int c3 = 0; c3 < 3; ++c3)
                    acc += xv[ic][r][c3] * wo[ic * 9 + r * 3 + c3];
        h[(size_t)(b * CH + o) * HW + hr * W + w] = f2bf(acc);
    }
}

// ---------------- DFT along W: h(bf16) rows -> Xw[row][k]{re,im} ------------
// v3 structure (r14-proven): float4-granular conflict-free staging; 256 thr:
// (r=tid&63, kp=tid>>6 wave-uniform) owns 3 modes; twiddles -> s_load.
__global__ __launch_bounds__(256) void k_dft_w(
        const u16* __restrict__ h, const float* __restrict__ cnsWkw,
        float* __restrict__ Xw) {
    __shared__ float xs[64 * 129];       // 33 KB
    int row0 = blockIdx.x * 64;
    int tid = threadIdx.x;
    const uint2* src = (const uint2*)h;  // 4 bf16 per uint2
    #pragma unroll
    for (int it = 0; it < 8; ++it) {     // 2048 float4-slots, conflict-free
        int idx = it * 256 + tid;
        int r = idx >> 5, f4c = idx & 31;
        uint2 v = src[(size_t)(row0 + r) * 32 + f4c];
        float4 f;
        f.x = bflo(v.x); f.y = bfhi(v.x);
        f.z = bflo(v.y); f.w = bfhi(v.y);
        *(float4*)(xs + r * 129 + f4c * 4) = f;
    }
    __syncthreads();
    int r = tid & 63;
    int kp = __builtin_amdgcn_readfirstlane(tid >> 6);   // 0..3, wave-uniform
    const f32x2* tw = (const f32x2*)cnsWkw + kp * 3 * W; // k = 3kp..3kp+2
    f32x2 a0 = mk2(0.f, 0.f), a1 = mk2(0.f, 0.f), a2 = mk2(0.f, 0.f);
    const float* xr = xs + r * 129;
    #pragma unroll 4
    for (int w = 0; w < W; ++w) {
        float xv = xr[w];                // ds_read_b32, 2-way max (free)
        f32x2 x2 = mk2(xv, xv);
        a0 += x2 * tw[w];                // uniform -> s_load + v_pk_fma
        a1 += x2 * tw[W + w];
        a2 += x2 * tw[2 * W + w];
    }
    float2* dst = (float2*)(Xw + (size_t)(row0 + r) * MODES * 2) + kp * 3;
    dst[0] = make_float2(a0.x, a0.y);
    dst[1] = make_float2(a1.x, a1.y);
    dst[2] = make_float2(a2.x, a2.y);
}

// ---------------- DFT along H: Xw -> Xf[m][b*CH+c]{re,im} -------------------
__global__ __launch_bounds__(320) void k_dft_h(
        const float* __restrict__ Xw, const float* __restrict__ cnsH2,
        float* __restrict__ Xf) {
    __shared__ float4 xs4[H * KX / 2];   // 12 KB, aliased as float2[H][KX]
    const float2* xs = (const float2*)xs4;
    int bc = blockIdx.x;                 // 0..B*CH-1
    int tid = threadIdx.x;               // 0..319
    const float4* src = (const float4*)(Xw + (size_t)bc * H * KX * 2);
    #pragma unroll
    for (int r = 0; r < 3; ++r) {        // 768 float4 staged by 320 threads
        int idx = r * 320 + tid;
        if (idx < H * KX / 2) xs4[idx] = src[idx];
    }
    __syncthreads();
    if (tid < KY * KX) {                 // m = tid = ky*KX+kx
        int ky = tid / KX, kx = tid % KX;
        const float2* cs = (const float2*)cnsH2 + ky;   // [hh][ky] stride KY
        float ar = 0.f, ai = 0.f;
        #pragma unroll 4
        for (int hh = 0; hh < H; ++hh) {
            float2 v = xs[hh * KX + kx];                 // LDS broadcast groups
            float2 t = cs[hh * KY];                      // L1-resident table
            ar += v.x * t.x + v.y * t.y;                 // (xr+ixi)(c-is)
            ai += v.y * t.x - v.x * t.y;
        }
        ((float2*)Xf)[(size_t)tid * (B * CH) + bc] = make_float2(ar, ai);
    }
}

// ---------------- spectral channel mix: per mode, Y[b,o] = sum_i X[b,i]W[i,o]
__global__ __launch_bounds__(256) void k_specmul(
        const float* __restrict__ Xf, const float* __restrict__ wRl,
        float* __restrict__ Yt) {
    int m = blockIdx.x;                 // 0..287
    int o = threadIdx.x & 31;
    int bq = threadIdx.x >> 5;          // 0..7 -> 8 b's each
    const f32x2* X  = (const f32x2*)Xf  + (size_t)m * (B * CH);
    const f32x2* Wm = (const f32x2*)wRl + (size_t)m * (CH * CH);
    f32x2 acc2[8];
    #pragma unroll
    for (int j = 0; j < 8; ++j) acc2[j] = mk2(0.f, 0.f);
    for (int i = 0; i < CH; ++i) {
        f32x2 wv  = Wm[i * CH + o];     // coalesced across lanes
        f32x2 wvB = mk2(-wv.y, wv.x);
        #pragma unroll
        for (int j = 0; j < 8; ++j) {
            f32x2 xv = X[(bq * 8 + j) * CH + i];   // L1/L2 broadcast
            acc2[j] += mk2(xv.x, xv.x) * wv + mk2(xv.y, xv.y) * wvB;  // 2 pk_fma
        }
    }
    float2* Yp = (float2*)Yt;
    #pragma unroll
    for (int j = 0; j < 8; ++j)
        Yp[((size_t)(bq * 8 + j) * NMODE + m) * CH + o] = make_float2(acc2[j].x, acc2[j].y);
}

// ---------------- inverse DFT along H: Yt -> Zt[b][h][p][kx][o], pre-scaled -
__global__ __launch_bounds__(384) void k_idft_h(
        const float* __restrict__ Yt, const float* __restrict__ cnsH2,
        const float* __restrict__ mnsH2, float* __restrict__ Zt) {
    int b = blockIdx.x;
    int hh0 = blockIdx.y * 16;           // 8 chunks of 16 rows
    int o = threadIdx.x & 31;
    int kx = threadIdx.x >> 5;           // 0..11
    float yr[KY], yi[KY];
    #pragma unroll
    for (int ky = 0; ky < KY; ++ky) {
        float2 v = ((const float2*)Yt)[((size_t)b * NMODE + ky * KX + kx) * CH + o];
        yr[ky] = v.x;  yi[ky] = v.y;
    }
    float sc = (kx == 0 ? 1.0f : 2.0f) / (float)HW;
    #pragma unroll 2
    for (int hr = 0; hr < 16; ++hr) {
        int hh = hh0 + hr;
        const f32x2* cs = (const f32x2*)(cnsH2 + hh * KY * 2);  // uniform
        const f32x2* ms = (const f32x2*)(mnsH2 + hh * KY * 2);  // uniform
        f32x2 a = mk2(0.f, 0.f);
        #pragma unroll
        for (int ky = 0; ky < KY; ++ky)
            a += mk2(yr[ky], yr[ky]) * cs[ky] + mk2(yi[ky], yi[ky]) * ms[ky];
        size_t base = ((size_t)(b * H + hh) * 2) * (KX * CH) + kx * CH + o;
        Zt[base]            = a.x * sc;
        Zt[base + KX * CH]  = a.y * sc;
    }
}

// ---------------- fused: pointwise GEMM + irfft(W) + bias + GELU ------------
// r14 pk body + packed gelu2 + cvt_pk bf16 stores. LAST=0: write gelu(h) in
// place. LAST=1: per-block partials -> part (no global atomics).
template <int LAST>
__global__ __launch_bounds__(512, 4) void k_fused(
        u16* __restrict__ h, const float* __restrict__ Zt,
        const float* __restrict__ wwT, const float* __restrict__ wb,
        const float* __restrict__ cWkw, const float* __restrict__ sWkw,
        float* __restrict__ part) {
    __shared__ float hs[CH * W];         // 16 KB
    __shared__ float red[8][8];          // wave partials (LAST=1 only)
    int bh = blockIdx.x;                 // b*H + hr
    int b = bh >> 7, hr = bh & 127;
    int tid = threadIdx.x;
    int w = tid & 127;
    int og = __builtin_amdgcn_readfirstlane(tid >> 7);   // wave-uniform 0..3
    const uint2* hrow2 = (const uint2*)(h + (size_t)b * CH * HW + hr * W);
    #pragma unroll
    for (int p = 0; p < 2; ++p) {        // 1024 float4-slots, conflict-free
        int idx = p * 512 + tid;
        int i = idx >> 5, f4c = idx & 31;
        uint2 v = hrow2[(size_t)i * (HW / 4) + f4c];
        float4 f;
        f.x = bflo(v.x); f.y = bfhi(v.x);
        f.z = bflo(v.y); f.w = bfhi(v.y);
        *(float4*)(hs + i * W + f4c * 4) = f;
    }
    float ck[MODES], nsk[MODES];
    #pragma unroll
    for (int k = 0; k < MODES; ++k) {
        ck[k]  = cWkw[k * W + w];        // per-lane, coalesced, L1-hot
        nsk[k] = -sWkw[k * W + w];
    }
    f32x2 acc2[4];
    const f32x2* wb2 = (const f32x2*)(wb + og * 8);      // uniform
    #pragma unroll
    for (int j = 0; j < 4; ++j) acc2[j] = wb2[j];
    __syncthreads();
    // pointwise: acc2[j] += hs[i][w] * wwT[i][og*8+2j..2j+1]
    #pragma unroll 4
    for (int i = 0; i < CH; ++i) {
        float hv = hs[i * W + w];
        f32x2 hv2 = mk2(hv, hv);
        const f32x2* wt2 = (const f32x2*)(wwT + i * CH + og * 8);  // uniform
        #pragma unroll
        for (int j = 0; j < 4; ++j) acc2[j] += hv2 * wt2[j];       // pk_fma
    }
    // spectral: acc2[j] += zr*ck - zi*sk  (pre-scaled in Zt)
    const float* Zb = Zt + ((size_t)bh * 2) * (KX * CH) + og * 8;
    #pragma unroll
    for (int k = 0; k < MODES; ++k) {
        const f32x2* zr2 = (const f32x2*)(Zb + k * CH);            // uniform
        const f32x2* zi2 = (const f32x2*)(Zb + k * CH + KX * CH);
        f32x2 ck2  = mk2(ck[k], ck[k]);
        f32x2 nsk2 = mk2(nsk[k], nsk[k]);
        #pragma unroll
        for (int j = 0; j < 4; ++j)
            acc2[j] += zr2[j] * ck2 + zi2[j] * nsk2;               // 2 pk_fma
    }
    if (LAST == 0) {
        u16* hout = h + (size_t)(b * CH + og * 8) * HW + hr * W + w;
        #pragma unroll
        for (int j = 0; j < 4; ++j) {
            u32 pk = pk2bf(gelu2(acc2[j]));          // v_cvt_pk_bf16_f32
            hout[(size_t)(2 * j)     * HW] = (u16)pk;
            hout[(size_t)(2 * j + 1) * HW] = (u16)(pk >> 16);
        }
    } else {
        float v[8];
        #pragma unroll
        for (int j = 0; j < 4; ++j) {
            f32x2 g = gelu2(acc2[j]);
            v[2 * j]     = g.x;
            v[2 * j + 1] = g.y;
        }
        #pragma unroll
        for (int j = 0; j < 8; ++j)
            #pragma unroll
            for (int off = 32; off > 0; off >>= 1)
                v[j] += __shfl_xor(v[j], off, 64);
        int wave = tid >> 6;             // 0..7 (wave>>1 == og)
        if ((tid & 63) == 0) {
            #pragma unroll
            for (int j = 0; j < 8; ++j) red[wave][j] = v[j];
        }
        __syncthreads();
        if (tid < CH) {                  // c = tid: og=c>>3, j=c&7
            float p = red[2 * (tid >> 3)][tid & 7] + red[2 * (tid >> 3) + 1][tid & 7];
            part[((size_t)b * CH + tid) * H + hr] = p;
        }
    }
}

// ---------------- reduce partials -> g[b][c] (mean folded) ------------------
__global__ __launch_bounds__(64) void k_reduce(
        const float* __restrict__ part, float* __restrict__ g) {
    int bc = blockIdx.x;                 // 0..B*CH-1
    int t = threadIdx.x;                 // 0..63
    float s = part[(size_t)bc * H + t] + part[(size_t)bc * H + 64 + t];
    #pragma unroll
    for (int off = 32; off > 0; off >>= 1) s += __shfl_down(s, off, 64);
    if (t == 0) g[bc] = s * (1.0f / (float)HW);
}

// ---------------- head MLP: 32 -> 128 gelu -> 1 -> sigmoid ------------------
__global__ __launch_bounds__(128) void k_head(
        const float* __restrict__ g, const float* __restrict__ q1w,
        const float* __restrict__ q1b, const float* __restrict__ q2w,
        const float* __restrict__ q2b, float* __restrict__ out) {
    __shared__ float gs[CH];
    __shared__ float red2[2];
    int b = blockIdx.x;
    int t = threadIdx.x;
    if (t < CH) gs[t] = g[b * CH + t];
    __syncthreads();
    float a = q1b[t];
    #pragma unroll
    for (int c = 0; c < CH; ++c) a += gs[c] * q1w[t * CH + c];
    a = gelu_f(a);
    float hsum = a * q2w[t];
    #pragma unroll
    for (int off = 32; off > 0; off >>= 1) hsum += __shfl_down(hsum, off, 64);
    if ((t & 63) == 0) red2[t >> 6] = hsum;
    __syncthreads();
    if (t == 0) {
        float logit = red2[0] + red2[1] + q2b[0];
        out[b] = 1.0f / (1.0f + expf(-logit));
    }
}

extern "C" void kernel_launch(void* const* d_in, const int* in_sizes, int n_in,
                              void* d_out, int out_size, void* d_ws, size_t ws_size,
                              hipStream_t stream) {
    const float* x   = (const float*)d_in[0];
    const float* p_w = (const float*)d_in[1];
    const float* p_b = (const float*)d_in[2];
    const float* w1r = (const float*)d_in[3];
    const float* w1i = (const float*)d_in[4];
    const float* w2r = (const float*)d_in[5];
    const float* w2i = (const float*)d_in[6];
    const float* ww  = (const float*)d_in[7];
    const float* wb  = (const float*)d_in[8];
    const float* q1w = (const float*)d_in[9];
    const float* q1b = (const float*)d_in[10];
    const float* q2w = (const float*)d_in[11];
    const float* q2b = (const float*)d_in[12];
    float* out = (float*)d_out;

    float* ws = (float*)d_ws;
    size_t off = 0;
    auto alloc = [&](size_t n) {
        float* p = ws + off;
        off += (n + 63) & ~(size_t)63;   // 256B-align
        return p;
    };
    float* cWkw   = alloc(MODES * W);
    float* sWkw   = alloc(MODES * W);
    float* cnsWkw = alloc(MODES * W * 2);
    float* cnsH2  = alloc(H * KY * 2);
    float* mnsH2  = alloc(H * KY * 2);
    u16*   hBuf = (u16*)alloc((size_t)B * CH * HW / 2);  // 67 MB bf16
    float* XwZ  = alloc((size_t)B * CH * H * KX * 2);    // 25 MB (Xw, reused as Zt)
    float* Xf   = alloc((size_t)NMODE * B * CH * 2);     // 4.7 MB
    float* Yt   = alloc((size_t)B * NMODE * CH * 2);     // 4.7 MB
    float* wR   = alloc((size_t)4 * NMODE * CH * CH * 2);// 9.4 MB
    float* wwT  = alloc(4 * CH * CH);
    float* part = alloc((size_t)B * CH * H);             // 1 MB block partials
    float* g    = alloc(B * CH);

    // one setup kernel: tables + ww transpose + weight reorder
    k_setup<<<(N_TBL + N_TRN + N_REO + 255) / 256, 256, 0, stream>>>(
        cWkw, sWkw, cnsWkw, cnsH2, mnsH2, w1r, w1i, w2r, w2i, wR, ww, wwT);

    k_lift<<<B * H, 128, 0, stream>>>(x, p_w, p_b, hBuf);

    for (int layer = 0; layer < 4; ++layer) {
        k_dft_w<<<(B * CH * H) / 64, 256, 0, stream>>>(hBuf, cnsWkw, XwZ);
        k_dft_h<<<B * CH, 320, 0, stream>>>(XwZ, cnsH2, Xf);
        k_specmul<<<NMODE, 256, 0, stream>>>(
            Xf, wR + (size_t)layer * NMODE * CH * CH * 2, Yt);
        k_idft_h<<<dim3(B, 8), 384, 0, stream>>>(Yt, cnsH2, mnsH2, XwZ);
        if (layer < 3)
            k_fused<0><<<B * H, 512, 0, stream>>>(
                hBuf, XwZ, wwT + layer * CH * CH, wb + layer * CH, cWkw, sWkw, part);
        else
            k_fused<1><<<B * H, 512, 0, stream>>>(
                hBuf, XwZ, wwT + layer * CH * CH, wb + layer * CH, cWkw, sWkw, part);
    }

    k_reduce<<<B * CH, 64, 0, stream>>>(part, g);
    k_head<<<B, 128, 0, stream>>>(g, q1w, q1b, q2w, q2b, out);
}

// Round 16
// 731.238 us; speedup vs baseline: 1.0305x; 1.0156x over previous
//
#include <hip/hip_runtime.h>
#include <hip/hip_bf16.h>
#include <math.h>

#define B 64
#define CIN 2
#define CH 32
#define H 128
#define W 128
#define MODES 12
#define KY 24              // kept ky rows: 0..11 and 116..127
#define KX 12              // kept kx cols
#define HW (H*W)           // 16384
#define NMODE (KY*KX)      // 288
#define XPAD 132           // LDS row pitch: 132 % 32 == 4 -> b128 banks rotate

typedef float f32x2 __attribute__((ext_vector_type(2)));
typedef unsigned short u16;
typedef unsigned int u32;
__device__ __forceinline__ f32x2 mk2(float a, float b) { f32x2 r; r.x = a; r.y = b; return r; }

// bf16 <-> f32 (h stored as bf16: halves h HBM traffic)
__device__ __forceinline__ float bflo(u32 u) { return __uint_as_float(u << 16); }
__device__ __forceinline__ float bfhi(u32 u) { return __uint_as_float(u & 0xFFFF0000u); }
__device__ __forceinline__ u16 f2bf(float f) {            // RTNE (lift only)
    u32 u = __float_as_uint(f);
    return (u16)((u + 0x7FFFu + ((u >> 16) & 1u)) >> 16);
}
// packed f32x2 -> 2 bf16 in one u32 (compiler: v_cvt_pk_bf16_f32)
__device__ __forceinline__ u32 pk2bf(f32x2 v) {
    __hip_bfloat162 p = __float22bfloat162_rn(make_float2(v.x, v.y));
    return *reinterpret_cast<u32*>(&p);
}

// tanh-form GELU. scalar (head/lift) ...
__device__ __forceinline__ float gelu_f(float x) {
    float x2 = x * x;
    float d  = x * (1.5957691216057308f + 0.0713548162726009f * x2);  // 2y
    float e  = __expf(d);
    float r  = __builtin_amdgcn_rcpf(e + 1.0f);
    return x - x * r;
}
// ... and packed-pair version for fused.
__device__ __forceinline__ f32x2 gelu2(f32x2 x) {
    const f32x2 c1 = mk2(1.5957691216057308f, 1.5957691216057308f);
    const f32x2 c2 = mk2(0.0713548162726009f, 0.0713548162726009f);
    f32x2 x2 = x * x;                        // pk_mul
    f32x2 d  = x * (c1 + c2 * x2);           // pk_fma + pk_mul
    f32x2 e  = mk2(__expf(d.x), __expf(d.y));
    f32x2 ep = e + mk2(1.0f, 1.0f);          // pk_add
    f32x2 r  = mk2(__builtin_amdgcn_rcpf(ep.x), __builtin_amdgcn_rcpf(ep.y));
    return x - x * r;
}

// ---------------- one setup kernel (tables + weight reorder + ww transpose) -
#define N_TBL (MODES * W + KY * H)           // 4608
#define N_TRN (4 * CH * CH)                  // 4096
#define N_REO (4 * NMODE * CH * CH)          // 1179648
__global__ __launch_bounds__(256) void k_setup(
        float* cWkw, float* sWkw, float* cnsWkw, float* cnsH2, float* mnsH2,
        const float* __restrict__ w1r, const float* __restrict__ w1i,
        const float* __restrict__ w2r, const float* __restrict__ w2i,
        float* __restrict__ wR,
        const float* __restrict__ ww, float* __restrict__ wwT) {
    int t = blockIdx.x * 256 + threadIdx.x;
    const float TWO_PI_OVER = 6.283185307179586476925f / 128.0f;
    if (t < MODES * W) {
        int k = t / W, w = t % W;
        int m = (k * w) & 127;
        float s, c;
        sincosf(TWO_PI_OVER * (float)m, &s, &c);
        cWkw[k * W + w] = c;  sWkw[k * W + w] = s;
        cnsWkw[(k * W + w) * 2]     = c;
        cnsWkw[(k * W + w) * 2 + 1] = -s;
    } else if (t < N_TBL) {
        int u = t - MODES * W;
        int kyI = u / H, hh = u % H;
        int ky = (kyI < MODES) ? kyI : (H - MODES + (kyI - MODES));  // 116..127
        int m = (ky * hh) & 127;
        float s, c;
        sincosf(TWO_PI_OVER * (float)m, &s, &c);
        cnsH2[(hh * KY + kyI) * 2]     = c;
        cnsH2[(hh * KY + kyI) * 2 + 1] = s;
        mnsH2[(hh * KY + kyI) * 2]     = -s;
        mnsH2[(hh * KY + kyI) * 2 + 1] = c;
    } else if (t < N_TBL + N_TRN) {
        int idx = t - N_TBL;
        int l = idx / (CH * CH);
        int r = idx % (CH * CH);
        int i = r / CH, o = r % CH;
        wwT[idx] = ww[l * CH * CH + o * CH + i];
    } else {
        int idx = t - N_TBL - N_TRN;
        if (idx >= N_REO) return;
        int o = idx & 31;
        int i = (idx >> 5) & 31;
        int m = (idx >> 10) % NMODE;
        int layer = idx / (NMODE * CH * CH);
        int kyI = m / KX, kx = m % KX;
        const float *sr, *si;
        int row;
        if (kyI < MODES) { sr = w1r; si = w1i; row = kyI; }
        else             { sr = w2r; si = w2i; row = kyI - MODES; }
        int src = ((layer * CH + i) * CH + o) * (MODES * MODES) + row * MODES + kx;
        wR[(size_t)idx * 2]     = sr[src];
        wR[(size_t)idx * 2 + 1] = si[src];
    }
}

// ---------------- lifting conv3x3 circular: x[B,2,H,W] -> h(bf16) -----------
__global__ __launch_bounds__(128) void k_lift(
        const float* __restrict__ x, const float* __restrict__ pw,
        const float* __restrict__ pb, u16* __restrict__ h) {
    int bh = blockIdx.x;            // b*H + hr
    int b = bh >> 7, hr = bh & 127;
    int w = threadIdx.x;
    int wl = (w + W - 1) & (W - 1), wr2 = (w + 1) & (W - 1);
    float xv[CIN][3][3];
    #pragma unroll
    for (int ic = 0; ic < CIN; ++ic) {
        const float* xc = x + (size_t)(b * CIN + ic) * HW;
        #pragma unroll
        for (int r = 0; r < 3; ++r) {
            int hh = (hr + r - 1 + H) & (H - 1);
            const float* xr = xc + hh * W;
            xv[ic][r][0] = xr[wl];
            xv[ic][r][1] = xr[w];
            xv[ic][r][2] = xr[wr2];
        }
    }
    for (int o = 0; o < CH; ++o) {
        float acc = pb[o];                       // uniform -> s_load
        const float* wo = pw + o * CIN * 9;      // uniform
        #pragma unroll
        for (int ic = 0; ic < CIN; ++ic)
            #pragma unroll
            for (int r = 0; r < 3; ++r)
                #pragma unroll
                for (int c3 = 0; c3 < 3; ++c3)
                    acc += xv[ic][r][c3] * wo[ic * 9 + r * 3 + c3];
        h[(size_t)(b * CH + o) * HW + hr * W + w] = f2bf(acc);
    }
}

// ---------------- DFT along W: h(bf16) rows -> Xw[row][k]{re,im} ------------
// v5: LDS pitch 132 (== 4 mod 32) so ds_read_b128 start banks rotate by 4
// per lane -> inherent-minimum aliasing, no excess conflict. Main loop reads
// float4 (one b128 replaces 4 b32: ~2x LDS pipe cut vs r15). 3 modes/thread
// (6 VGPR acc, no-spill); twiddles wave-uniform -> batched s_loads.
__global__ __launch_bounds__(256) void k_dft_w(
        const u16* __restrict__ h, const float* __restrict__ cnsWkw,
        float* __restrict__ Xw) {
    __shared__ float xs[64 * XPAD];      // 33.8 KB
    int row0 = blockIdx.x * 64;
    int tid = threadIdx.x;
    const uint2* src = (const uint2*)h;  // 4 bf16 per uint2
    #pragma unroll
    for (int it = 0; it < 8; ++it) {     // 2048 float4-slots, rotated banks
        int idx = it * 256 + tid;
        int r = idx >> 5, f4c = idx & 31;
        uint2 v = src[(size_t)(row0 + r) * 32 + f4c];
        float4 f;
        f.x = bflo(v.x); f.y = bfhi(v.x);
        f.z = bflo(v.y); f.w = bfhi(v.y);
        *(float4*)(xs + r * XPAD + f4c * 4) = f;
    }
    __syncthreads();
    int r = tid & 63;
    int kp = __builtin_amdgcn_readfirstlane(tid >> 6);   // 0..3, wave-uniform
    const f32x2* tw = (const f32x2*)cnsWkw + kp * 3 * W; // k = 3kp..3kp+2
    f32x2 a0 = mk2(0.f, 0.f), a1 = mk2(0.f, 0.f), a2 = mk2(0.f, 0.f);
    const float4* xr4 = (const float4*)(xs + r * XPAD);
    #pragma unroll 4
    for (int w4 = 0; w4 < W / 4; ++w4) {
        float4 xv = xr4[w4];             // ds_read_b128, optimal banking
        int w = w4 * 4;
        const f32x2* t0 = tw + w;        // uniform -> s_load_dwordx8
        const f32x2* t1 = tw + W + w;
        const f32x2* t2 = tw + 2 * W + w;
        float xa0 = xv.x, xa1 = xv.y, xa2 = xv.z, xa3 = xv.w;
        a0 += mk2(xa0, xa0) * t0[0];  a1 += mk2(xa0, xa0) * t1[0];  a2 += mk2(xa0, xa0) * t2[0];
        a0 += mk2(xa1, xa1) * t0[1];  a1 += mk2(xa1, xa1) * t1[1];  a2 += mk2(xa1, xa1) * t2[1];
        a0 += mk2(xa2, xa2) * t0[2];  a1 += mk2(xa2, xa2) * t1[2];  a2 += mk2(xa2, xa2) * t2[2];
        a0 += mk2(xa3, xa3) * t0[3];  a1 += mk2(xa3, xa3) * t1[3];  a2 += mk2(xa3, xa3) * t2[3];
    }
    float2* dst = (float2*)(Xw + (size_t)(row0 + r) * MODES * 2) + kp * 3;
    dst[0] = make_float2(a0.x, a0.y);
    dst[1] = make_float2(a1.x, a1.y);
    dst[2] = make_float2(a2.x, a2.y);
}

// ---------------- DFT along H: Xw -> Xf[m][b*CH+c]{re,im} -------------------
__global__ __launch_bounds__(320) void k_dft_h(
        const float* __restrict__ Xw, const float* __restrict__ cnsH2,
        float* __restrict__ Xf) {
    __shared__ float4 xs4[H * KX / 2];   // 12 KB, aliased as float2[H][KX]
    const float2* xs = (const float2*)xs4;
    int bc = blockIdx.x;                 // 0..B*CH-1
    int tid = threadIdx.x;               // 0..319
    const float4* src = (const float4*)(Xw + (size_t)bc * H * KX * 2);
    #pragma unroll
    for (int r = 0; r < 3; ++r) {        // 768 float4 staged by 320 threads
        int idx = r * 320 + tid;
        if (idx < H * KX / 2) xs4[idx] = src[idx];
    }
    __syncthreads();
    if (tid < KY * KX) {                 // m = tid = ky*KX+kx
        int ky = tid / KX, kx = tid % KX;
        const float2* cs = (const float2*)cnsH2 + ky;   // [hh][ky] stride KY
        float ar = 0.f, ai = 0.f;
        #pragma unroll 4
        for (int hh = 0; hh < H; ++hh) {
            float2 v = xs[hh * KX + kx];                 // LDS broadcast groups
            float2 t = cs[hh * KY];                      // L1-resident table
            ar += v.x * t.x + v.y * t.y;                 // (xr+ixi)(c-is)
            ai += v.y * t.x - v.x * t.y;
        }
        ((float2*)Xf)[(size_t)tid * (B * CH) + bc] = make_float2(ar, ai);
    }
}

// ---------------- spectral channel mix: per mode, Y[b,o] = sum_i X[b,i]W[i,o]
__global__ __launch_bounds__(256) void k_specmul(
        const float* __restrict__ Xf, const float* __restrict__ wRl,
        float* __restrict__ Yt) {
    int m = blockIdx.x;                 // 0..287
    int o = threadIdx.x & 31;
    int bq = threadIdx.x >> 5;          // 0..7 -> 8 b's each
    const f32x2* X  = (const f32x2*)Xf  + (size_t)m * (B * CH);
    const f32x2* Wm = (const f32x2*)wRl + (size_t)m * (CH * CH);
    f32x2 acc2[8];
    #pragma unroll
    for (int j = 0; j < 8; ++j) acc2[j] = mk2(0.f, 0.f);
    for (int i = 0; i < CH; ++i) {
        f32x2 wv  = Wm[i * CH + o];     // coalesced across lanes
        f32x2 wvB = mk2(-wv.y, wv.x);
        #pragma unroll
        for (int j = 0; j < 8; ++j) {
            f32x2 xv = X[(bq * 8 + j) * CH + i];   // L1/L2 broadcast
            acc2[j] += mk2(xv.x, xv.x) * wv + mk2(xv.y, xv.y) * wvB;  // 2 pk_fma
        }
    }
    float2* Yp = (float2*)Yt;
    #pragma unroll
    for (int j = 0; j < 8; ++j)
        Yp[((size_t)(bq * 8 + j) * NMODE + m) * CH + o] = make_float2(acc2[j].x, acc2[j].y);
}

// ---------------- inverse DFT along H: Yt -> Zt[b][h][p][kx][o], pre-scaled -
__global__ __launch_bounds__(384) void k_idft_h(
        const float* __restrict__ Yt, const float* __restrict__ cnsH2,
        const float* __restrict__ mnsH2, float* __restrict__ Zt) {
    int b = blockIdx.x;
    int hh0 = blockIdx.y * 16;           // 8 chunks of 16 rows
    int o = threadIdx.x & 31;
    int kx = threadIdx.x >> 5;           // 0..11
    float yr[KY], yi[KY];
    #pragma unroll
    for (int ky = 0; ky < KY; ++ky) {
        float2 v = ((const float2*)Yt)[((size_t)b * NMODE + ky * KX + kx) * CH + o];
        yr[ky] = v.x;  yi[ky] = v.y;
    }
    float sc = (kx == 0 ? 1.0f : 2.0f) / (float)HW;
    #pragma unroll 2
    for (int hr = 0; hr < 16; ++hr) {
        int hh = hh0 + hr;
        const f32x2* cs = (const f32x2*)(cnsH2 + hh * KY * 2);  // uniform
        const f32x2* ms = (const f32x2*)(mnsH2 + hh * KY * 2);  // uniform
        f32x2 a = mk2(0.f, 0.f);
        #pragma unroll
        for (int ky = 0; ky < KY; ++ky)
            a += mk2(yr[ky], yr[ky]) * cs[ky] + mk2(yi[ky], yi[ky]) * ms[ky];
        size_t base = ((size_t)(b * H + hh) * 2) * (KX * CH) + kx * CH + o;
        Zt[base]            = a.x * sc;
        Zt[base + KX * CH]  = a.y * sc;
    }
}

// ---------------- fused: pointwise GEMM + irfft(W) + bias + GELU ------------
// r15 body frozen (84.5us; VALU cuts no longer move it). LAST=0: write
// gelu(h) in place. LAST=1: per-block partials -> part (no global atomics).
template <int LAST>
__global__ __launch_bounds__(512, 4) void k_fused(
        u16* __restrict__ h, const float* __restrict__ Zt,
        const float* __restrict__ wwT, const float* __restrict__ wb,
        const float* __restrict__ cWkw, const float* __restrict__ sWkw,
        float* __restrict__ part) {
    __shared__ float hs[CH * W];         // 16 KB
    __shared__ float red[8][8];          // wave partials (LAST=1 only)
    int bh = blockIdx.x;                 // b*H + hr
    int b = bh >> 7, hr = bh & 127;
    int tid = threadIdx.x;
    int w = tid & 127;
    int og = __builtin_amdgcn_readfirstlane(tid >> 7);   // wave-uniform 0..3
    const uint2* hrow2 = (const uint2*)(h + (size_t)b * CH * HW + hr * W);
    #pragma unroll
    for (int p = 0; p < 2; ++p) {        // 1024 float4-slots, conflict-free
        int idx = p * 512 + tid;
        int i = idx >> 5, f4c = idx & 31;
        uint2 v = hrow2[(size_t)i * (HW / 4) + f4c];
        float4 f;
        f.x = bflo(v.x); f.y = bfhi(v.x);
        f.z = bflo(v.y); f.w = bfhi(v.y);
        *(float4*)(hs + i * W + f4c * 4) = f;
    }
    float ck[MODES], nsk[MODES];
    #pragma unroll
    for (int k = 0; k < MODES; ++k) {
        ck[k]  = cWkw[k * W + w];        // per-lane, coalesced, L1-hot
        nsk[k] = -sWkw[k * W + w];
    }
    f32x2 acc2[4];
    const f32x2* wb2 = (const f32x2*)(wb + og * 8);      // uniform
    #pragma unroll
    for (int j = 0; j < 4; ++j) acc2[j] = wb2[j];
    __syncthreads();
    // pointwise: acc2[j] += hs[i][w] * wwT[i][og*8+2j..2j+1]
    #pragma unroll 4
    for (int i = 0; i < CH; ++i) {
        float hv = hs[i * W + w];
        f32x2 hv2 = mk2(hv, hv);
        const f32x2* wt2 = (const f32x2*)(wwT + i * CH + og * 8);  // uniform
        #pragma unroll
        for (int j = 0; j < 4; ++j) acc2[j] += hv2 * wt2[j];       // pk_fma
    }
    // spectral: acc2[j] += zr*ck - zi*sk  (pre-scaled in Zt)
    const float* Zb = Zt + ((size_t)bh * 2) * (KX * CH) + og * 8;
    #pragma unroll
    for (int k = 0; k < MODES; ++k) {
        const f32x2* zr2 = (const f32x2*)(Zb + k * CH);            // uniform
        const f32x2* zi2 = (const f32x2*)(Zb + k * CH + KX * CH);
        f32x2 ck2  = mk2(ck[k], ck[k]);
        f32x2 nsk2 = mk2(nsk[k], nsk[k]);
        #pragma unroll
        for (int j = 0; j < 4; ++j)
            acc2[j] += zr2[j] * ck2 + zi2[j] * nsk2;               // 2 pk_fma
    }
    if (LAST == 0) {
        u16* hout = h + (size_t)(b * CH + og * 8) * HW + hr * W + w;
        #pragma unroll
        for (int j = 0; j < 4; ++j) {
            u32 pk = pk2bf(gelu2(acc2[j]));          // v_cvt_pk_bf16_f32
            hout[(size_t)(2 * j)     * HW] = (u16)pk;
            hout[(size_t)(2 * j + 1) * HW] = (u16)(pk >> 16);
        }
    } else {
        float v[8];
        #pragma unroll
        for (int j = 0; j < 4; ++j) {
            f32x2 g = gelu2(acc2[j]);
            v[2 * j]     = g.x;
            v[2 * j + 1] = g.y;
        }
        #pragma unroll
        for (int j = 0; j < 8; ++j)
            #pragma unroll
            for (int off = 32; off > 0; off >>= 1)
                v[j] += __shfl_xor(v[j], off, 64);
        int wave = tid >> 6;             // 0..7 (wave>>1 == og)
        if ((tid & 63) == 0) {
            #pragma unroll
            for (int j = 0; j < 8; ++j) red[wave][j] = v[j];
        }
        __syncthreads();
        if (tid < CH) {                  // c = tid: og=c>>3, j=c&7
            float p = red[2 * (tid >> 3)][tid & 7] + red[2 * (tid >> 3) + 1][tid & 7];
            part[((size_t)b * CH + tid) * H + hr] = p;
        }
    }
}

// ---------------- reduce partials -> g[b][c] (mean folded) ------------------
__global__ __launch_bounds__(64) void k_reduce(
        const float* __restrict__ part, float* __restrict__ g) {
    int bc = blockIdx.x;                 // 0..B*CH-1
    int t = threadIdx.x;                 // 0..63
    float s = part[(size_t)bc * H + t] + part[(size_t)bc * H + 64 + t];
    #pragma unroll
    for (int off = 32; off > 0; off >>= 1) s += __shfl_down(s, off, 64);
    if (t == 0) g[bc] = s * (1.0f / (float)HW);
}

// ---------------- head MLP: 32 -> 128 gelu -> 1 -> sigmoid ------------------
__global__ __launch_bounds__(128) void k_head(
        const float* __restrict__ g, const float* __restrict__ q1w,
        const float* __restrict__ q1b, const float* __restrict__ q2w,
        const float* __restrict__ q2b, float* __restrict__ out) {
    __shared__ float gs[CH];
    __shared__ float red2[2];
    int b = blockIdx.x;
    int t = threadIdx.x;
    if (t < CH) gs[t] = g[b * CH + t];
    __syncthreads();
    float a = q1b[t];
    #pragma unroll
    for (int c = 0; c < CH; ++c) a += gs[c] * q1w[t * CH + c];
    a = gelu_f(a);
    float hsum = a * q2w[t];
    #pragma unroll
    for (int off = 32; off > 0; off >>= 1) hsum += __shfl_down(hsum, off, 64);
    if ((t & 63) == 0) red2[t >> 6] = hsum;
    __syncthreads();
    if (t == 0) {
        float logit = red2[0] + red2[1] + q2b[0];
        out[b] = 1.0f / (1.0f + expf(-logit));
    }
}

extern "C" void kernel_launch(void* const* d_in, const int* in_sizes, int n_in,
                              void* d_out, int out_size, void* d_ws, size_t ws_size,
                              hipStream_t stream) {
    const float* x   = (const float*)d_in[0];
    const float* p_w = (const float*)d_in[1];
    const float* p_b = (const float*)d_in[2];
    const float* w1r = (const float*)d_in[3];
    const float* w1i = (const float*)d_in[4];
    const float* w2r = (const float*)d_in[5];
    const float* w2i = (const float*)d_in[6];
    const float* ww  = (const float*)d_in[7];
    const float* wb  = (const float*)d_in[8];
    const float* q1w = (const float*)d_in[9];
    const float* q1b = (const float*)d_in[10];
    const float* q2w = (const float*)d_in[11];
    const float* q2b = (const float*)d_in[12];
    float* out = (float*)d_out;

    float* ws = (float*)d_ws;
    size_t off = 0;
    auto alloc = [&](size_t n) {
        float* p = ws + off;
        off += (n + 63) & ~(size_t)63;   // 256B-align
        return p;
    };
    float* cWkw   = alloc(MODES * W);
    float* sWkw   = alloc(MODES * W);
    float* cnsWkw = alloc(MODES * W * 2);
    float* cnsH2  = alloc(H * KY * 2);
    float* mnsH2  = alloc(H * KY * 2);
    u16*   hBuf = (u16*)alloc((size_t)B * CH * HW / 2);  // 67 MB bf16
    float* XwZ  = alloc((size_t)B * CH * H * KX * 2);    // 25 MB (Xw, reused as Zt)
    float* Xf   = alloc((size_t)NMODE * B * CH * 2);     // 4.7 MB
    float* Yt   = alloc((size_t)B * NMODE * CH * 2);     // 4.7 MB
    float* wR   = alloc((size_t)4 * NMODE * CH * CH * 2);// 9.4 MB
    float* wwT  = alloc(4 * CH * CH);
    float* part = alloc((size_t)B * CH * H);             // 1 MB block partials
    float* g    = alloc(B * CH);

    // one setup kernel: tables + ww transpose + weight reorder
    k_setup<<<(N_TBL + N_TRN + N_REO + 255) / 256, 256, 0, stream>>>(
        cWkw, sWkw, cnsWkw, cnsH2, mnsH2, w1r, w1i, w2r, w2i, wR, ww, wwT);

    k_lift<<<B * H, 128, 0, stream>>>(x, p_w, p_b, hBuf);

    for (int layer = 0; layer < 4; ++layer) {
        k_dft_w<<<(B * CH * H) / 64, 256, 0, stream>>>(hBuf, cnsWkw, XwZ);
        k_dft_h<<<B * CH, 320, 0, stream>>>(XwZ, cnsH2, Xf);
        k_specmul<<<NMODE, 256, 0, stream>>>(
            Xf, wR + (size_t)layer * NMODE * CH * CH * 2, Yt);
        k_idft_h<<<dim3(B, 8), 384, 0, stream>>>(Yt, cnsH2, mnsH2, XwZ);
        if (layer < 3)
            k_fused<0><<<B * H, 512, 0, stream>>>(
                hBuf, XwZ, wwT + layer * CH * CH, wb + layer * CH, cWkw, sWkw, part);
        else
            k_fused<1><<<B * H, 512, 0, stream>>>(
                hBuf, XwZ, wwT + layer * CH * CH, wb + layer * CH, cWkw, sWkw, part);
    }

    k_reduce<<<B * CH, 64, 0, stream>>>(part, g);
    k_head<<<B, 128, 0, stream>>>(g, q1w, q1b, q2w, q2b, out);
}